// Round 7
// baseline (224.105 us; speedup 1.0000x reference)
//
#include <hip/hip_runtime.h>
#include <hip/hip_bf16.h>

// MSDeformAttn: B=2, LQ=LV=11109, D=256, NH=8, HD=32, NL=3, NP=4
// shapes: (92,92),(46,46),(23,23); starts: 0, 8464, 10580
#define LQn   11109
#define MTOT  22218   // B * LQ

typedef __attribute__((ext_vector_type(8))) short short8;
typedef __attribute__((ext_vector_type(4))) float f32x4;

__device__ __forceinline__ unsigned short f2bf(float f) {
  union { float f; unsigned int u; } v; v.f = f;
  unsigned int r = v.u + 0x7fffu + ((v.u >> 16) & 1u);  // RNE
  return (unsigned short)(r >> 16);
}

// pack 8 fp32 -> 8 bf16 (RNE, v_cvt_pk_bf16_f32 on gfx950)
__device__ __forceinline__ short8 pack8(float4 a, float4 b) {
  union { __hip_bfloat162 h[4]; short8 s; } u;
  u.h[0] = __float22bfloat162_rn(make_float2(a.x, a.y));
  u.h[1] = __float22bfloat162_rn(make_float2(a.z, a.w));
  u.h[2] = __float22bfloat162_rn(make_float2(b.x, b.y));
  u.h[3] = __float22bfloat162_rn(make_float2(b.z, b.w));
  return u.s;
}

// ---------------- weight prep: coalesced reads, scattered (posted) writes ----------
// grid 256 (k), block 320 (n). Wcat_t/bcat padded to 320 rows (288..319 = 0).
__global__ __launch_bounds__(320) void prep_weights2(
    const float* __restrict__ Wval, const float* __restrict__ Woff,
    const float* __restrict__ Wattn, const float* __restrict__ Wout,
    const float* __restrict__ boff, const float* __restrict__ battn,
    unsigned short* __restrict__ Wval_t, unsigned short* __restrict__ Wcat_t,
    unsigned short* __restrict__ Wout_t, float* __restrict__ bcat) {
  const int k = blockIdx.x;    // 0..255
  const int n = threadIdx.x;   // 0..319
  if (n < 256) {
    Wval_t[n * 256 + k] = f2bf(Wval[k * 256 + n]);
    Wout_t[n * 256 + k] = f2bf(Wout[k * 256 + n]);
  }
  float c = (n < 192) ? Woff[k * 192 + n] : (n < 288 ? Wattn[k * 96 + (n - 192)] : 0.f);
  Wcat_t[n * 256 + k] = f2bf(c);
  if (k == 0) bcat[n] = (n < 192) ? boff[n] : (n < 288 ? battn[n - 192] : 0.f);
}

// ---------------- GEMM1+2: one wave per 64x64 tile, no LDS, no barriers ----------
// grid (348, 9): y<4 -> value proj (A=value fp32, Bt=Wval_t, bf16 head-major out)
//                y>=4 -> logits proj (A=query fp32, Bt=Wcat_t[320], fp32 out, N=288)
__global__ __launch_bounds__(64) void gemm12_tile(
    const float* __restrict__ Aval, const float* __restrict__ Aq,
    const unsigned short* __restrict__ Bval, const unsigned short* __restrict__ Bcat,
    const float* __restrict__ bval, const float* __restrict__ bcat,
    unsigned short* __restrict__ value16,    // [b][h][pix][32] bf16
    float* __restrict__ logits) {            // (M,288) fp32
  const int bm = blockIdx.x;
  int bn = blockIdx.y;
  const bool is2 = bn >= 4;
  if (is2) bn -= 4;
  const float* __restrict__ A = is2 ? Aq : Aval;
  const unsigned short* __restrict__ Bt = is2 ? Bcat : Bval;

  const int t = threadIdx.x;
  const int quad = t >> 4, l16 = t & 15;

  const float* aptr[4];
#pragma unroll
  for (int i = 0; i < 4; i++) {
    int r = bm * 64 + i * 16 + l16;
    r = (r < MTOT) ? r : (MTOT - 1);
    aptr[i] = A + (size_t)r * 256 + quad * 8;
  }
  const unsigned short* bptr[4];
#pragma unroll
  for (int j = 0; j < 4; j++)
    bptr[j] = Bt + (size_t)(bn * 64 + j * 16 + l16) * 256 + quad * 8;

  f32x4 acc[4][4];
#pragma unroll
  for (int i = 0; i < 4; i++)
#pragma unroll
    for (int j = 0; j < 4; j++) acc[i][j] = (f32x4){0.f, 0.f, 0.f, 0.f};

#pragma unroll
  for (int kb = 0; kb < 8; kb++) {
    short8 af[4], bfr[4];
#pragma unroll
    for (int i = 0; i < 4; i++) {
      float4 a0 = *(const float4*)(aptr[i] + kb * 32);
      float4 a1 = *(const float4*)(aptr[i] + kb * 32 + 4);
      af[i] = pack8(a0, a1);
    }
#pragma unroll
    for (int j = 0; j < 4; j++)
      bfr[j] = *(const short8*)(bptr[j] + kb * 32);
#pragma unroll
    for (int i = 0; i < 4; i++)
#pragma unroll
      for (int j = 0; j < 4; j++)
        acc[i][j] = __builtin_amdgcn_mfma_f32_16x16x32_bf16(af[i], bfr[j], acc[i][j], 0, 0, 0);
  }

  // D: col = l16, row = quad*4 + r
  if (!is2) {
#pragma unroll
    for (int j = 0; j < 4; j++) {
      const int col = bn * 64 + j * 16 + l16;       // < 256
      const float bs = bval[col];
      const int h = col >> 5, cch = col & 31;
#pragma unroll
      for (int i = 0; i < 4; i++) {
        const int row0 = bm * 64 + i * 16 + quad * 4;
#pragma unroll
        for (int r = 0; r < 4; r++) {
          const int rg = row0 + r;
          if (rg >= MTOT) continue;
          const int b = (rg >= LQn) ? 1 : 0;
          const int p = rg - b * LQn;
          value16[((size_t)(b * 8 + h) * LQn + p) * 32 + cch] = f2bf(acc[i][j][r] + bs);
        }
      }
    }
  } else {
#pragma unroll
    for (int j = 0; j < 4; j++) {
      const int col = bn * 64 + j * 16 + l16;
      if (col >= 288) continue;
      const float bs = bcat[col];
#pragma unroll
      for (int i = 0; i < 4; i++) {
        const int row0 = bm * 64 + i * 16 + quad * 4;
#pragma unroll
        for (int r = 0; r < 4; r++) {
          const int rg = row0 + r;
          if (rg < MTOT) logits[(size_t)rg * 288 + col] = acc[i][j][r] + bs;
        }
      }
    }
  }
}

// ---------------- GEMM3 (out proj): one wave per 64x64 tile, A bf16 ----------
__global__ __launch_bounds__(64) void gemm_out_tile(
    const unsigned short* __restrict__ A,    // (M,256) bf16
    const unsigned short* __restrict__ Bt,   // (256,256) bf16 N-major
    const float* __restrict__ bias,
    float* __restrict__ C) {                 // (M,256) fp32
  const int bm = blockIdx.x, bn = blockIdx.y;
  const int t = threadIdx.x;
  const int quad = t >> 4, l16 = t & 15;

  const unsigned short* aptr[4];
#pragma unroll
  for (int i = 0; i < 4; i++) {
    int r = bm * 64 + i * 16 + l16;
    r = (r < MTOT) ? r : (MTOT - 1);
    aptr[i] = A + (size_t)r * 256 + quad * 8;
  }
  const unsigned short* bptr[4];
#pragma unroll
  for (int j = 0; j < 4; j++)
    bptr[j] = Bt + (size_t)(bn * 64 + j * 16 + l16) * 256 + quad * 8;

  f32x4 acc[4][4];
#pragma unroll
  for (int i = 0; i < 4; i++)
#pragma unroll
    for (int j = 0; j < 4; j++) acc[i][j] = (f32x4){0.f, 0.f, 0.f, 0.f};

#pragma unroll
  for (int kb = 0; kb < 8; kb++) {
    short8 af[4], bfr[4];
#pragma unroll
    for (int i = 0; i < 4; i++) af[i] = *(const short8*)(aptr[i] + kb * 32);
#pragma unroll
    for (int j = 0; j < 4; j++) bfr[j] = *(const short8*)(bptr[j] + kb * 32);
#pragma unroll
    for (int i = 0; i < 4; i++)
#pragma unroll
      for (int j = 0; j < 4; j++)
        acc[i][j] = __builtin_amdgcn_mfma_f32_16x16x32_bf16(af[i], bfr[j], acc[i][j], 0, 0, 0);
  }

#pragma unroll
  for (int j = 0; j < 4; j++) {
    const int col = bn * 64 + j * 16 + l16;
    const float bs = bias[col];
#pragma unroll
    for (int i = 0; i < 4; i++) {
      const int row0 = bm * 64 + i * 16 + quad * 4;
#pragma unroll
      for (int r = 0; r < 4; r++) {
        const int rg = row0 + r;
        if (rg < MTOT) C[(size_t)rg * 256 + col] = acc[i][j][r] + bs;
      }
    }
  }
}

// ---------------- sampling + softmax + weighted sum, v5 (unchanged) ----------------
__global__ __launch_bounds__(256) void msda_sample5(
    const unsigned short* __restrict__ value16,  // [b][h][pix][32] bf16
    const float* __restrict__ logits,            // (M,288)
    const float* __restrict__ refp,              // (M,3,2) (y,x)
    unsigned short* __restrict__ sampled) {      // (M,256) bf16
  __shared__ float          tw[8][96][4];
  __shared__ unsigned short ti[8][96][4];
  __shared__ float hmx[8][8], hrd[8][8];
  __shared__ float rfs[8][6];

  const int t = threadIdx.x;
  const int qbase = blockIdx.x * 8;

  if (t < 48) {
    int q = t / 6;
    if (qbase + q < MTOT) rfs[q][t - q * 6] = refp[(size_t)qbase * 6 + t];
  }
  if (t >= 64 && t < 128) {
    int tt = t - 64;
    int q = tt >> 3, h = tt & 7;
    int bq = qbase + q;
    if (bq < MTOT) {
      const float* lrow = logits + (size_t)bq * 288 + 192 + h * 12;
      float mx = -1e30f;
#pragma unroll
      for (int i = 0; i < 12; i++) mx = fmaxf(mx, lrow[i]);
      float den = 0.f;
#pragma unroll
      for (int i = 0; i < 12; i++) den += __expf(lrow[i] - mx);
      hmx[q][h] = mx;
      hrd[q][h] = 1.0f / den;
    }
  }
  __syncthreads();

  {
    const int Hs[3] = {92, 46, 23};
    const int Ss[3] = {0, 8464, 10580};
#pragma unroll
    for (int r = 0; r < 3; r++) {
      const int task = t + r * 256;
      const int q = task / 96, s = task - q * 96;   // s = slot = pl*8 + h
      const int bq = qbase + q;
      if (bq < MTOT) {
        const int h = s & 7, pl = s >> 3;
        const int l = pl >> 2;
        const int H = Hs[l], W = Hs[l], S = Ss[l];
        const int ob = h * 12 + pl;
        const float* lrow = logits + (size_t)bq * 288;
        const float aw = __expf(lrow[192 + ob] - hmx[q][h]) * hrd[q][h];
        const float offy = lrow[2 * ob], offx = lrow[2 * ob + 1];
        const float x = rfs[q][l * 2 + 1] * W + offx - 0.5f;
        const float y = rfs[q][l * 2 + 0] * H + offy - 0.5f;
        const float xf = floorf(x), yf = floorf(y);
        const int x0 = (int)xf, y0 = (int)yf;
        const float lx = x - xf, ly = y - yf;
        const bool xv0 = (x0 >= 0) & (x0 < W), xv1 = (x0 + 1 >= 0) & (x0 + 1 < W);
        const bool yv0 = (y0 >= 0) & (y0 < H), yv1 = (y0 + 1 >= 0) & (y0 + 1 < H);
        const int xc0 = min(max(x0, 0), W - 1), xc1 = min(max(x0 + 1, 0), W - 1);
        const int yc0 = min(max(y0, 0), H - 1), yc1 = min(max(y0 + 1, 0), H - 1);
        ti[q][s][0] = (unsigned short)(S + yc0 * W + xc0);
        ti[q][s][1] = (unsigned short)(S + yc0 * W + xc1);
        ti[q][s][2] = (unsigned short)(S + yc1 * W + xc0);
        ti[q][s][3] = (unsigned short)(S + yc1 * W + xc1);
        tw[q][s][0] = (yv0 & xv0) ? aw * (1.f - ly) * (1.f - lx) : 0.f;
        tw[q][s][1] = (yv0 & xv1) ? aw * (1.f - ly) * lx : 0.f;
        tw[q][s][2] = (yv1 & xv0) ? aw * ly * (1.f - lx) : 0.f;
        tw[q][s][3] = (yv1 & xv1) ? aw * ly * lx : 0.f;
      }
    }
  }
  __syncthreads();

  {
    const int w = t >> 6, lane = t & 63;
    const int q = w * 2 + (lane >> 5);
    const int h = (lane >> 2) & 7, cg = lane & 3;
    const int bq = qbase + q;
    const bool qv = bq < MTOT;
    const int bqc = qv ? bq : 0;
    const char* __restrict__ vb =
        (const char*)value16 + (size_t)(bqc / LQn) * ((size_t)LQn * 512);
    const unsigned laneoff = (unsigned)h * (LQn * 64u) + (unsigned)cg * 16u;

    float a0 = 0.f, a1 = 0.f, a2 = 0.f, a3 = 0.f;
    float a4 = 0.f, a5 = 0.f, a6 = 0.f, a7 = 0.f;
#pragma unroll
    for (int p = 0; p < 12; p++) {
      const int slot = p * 8 + h;
      const ushort4 tiv = *(const ushort4*)(&ti[q][slot][0]);
      const f32x4 wv = *(const f32x4*)(&tw[q][slot][0]);
#pragma unroll
      for (int k = 0; k < 4; k++) {
        const unsigned pix =
            (k == 0) ? tiv.x : (k == 1) ? tiv.y : (k == 2) ? tiv.z : tiv.w;
        const float wgt = wv[k];
        const uint4 u = *(const uint4*)(vb + ((pix << 6) + laneoff));
        a0 += wgt * __uint_as_float(u.x << 16);
        a1 += wgt * __uint_as_float(u.x & 0xffff0000u);
        a2 += wgt * __uint_as_float(u.y << 16);
        a3 += wgt * __uint_as_float(u.y & 0xffff0000u);
        a4 += wgt * __uint_as_float(u.z << 16);
        a5 += wgt * __uint_as_float(u.z & 0xffff0000u);
        a6 += wgt * __uint_as_float(u.w << 16);
        a7 += wgt * __uint_as_float(u.w & 0xffff0000u);
      }
    }
    if (qv) {
      uint4 o;
      o.x = (unsigned)f2bf(a0) | ((unsigned)f2bf(a1) << 16);
      o.y = (unsigned)f2bf(a2) | ((unsigned)f2bf(a3) << 16);
      o.z = (unsigned)f2bf(a4) | ((unsigned)f2bf(a5) << 16);
      o.w = (unsigned)f2bf(a6) | ((unsigned)f2bf(a7) << 16);
      *(uint4*)(sampled + (size_t)bq * 256 + h * 32 + cg * 8) = o;
    }
  }
}

// ---------------- host launch ----------------
extern "C" void kernel_launch(void* const* d_in, const int* in_sizes, int n_in,
                              void* d_out, int out_size, void* d_ws, size_t ws_size,
                              hipStream_t stream) {
  const float* query      = (const float*)d_in[0];
  const float* refp       = (const float*)d_in[1];
  const float* value_flat = (const float*)d_in[2];
  const float* W_val      = (const float*)d_in[3];
  const float* b_val      = (const float*)d_in[4];
  const float* W_off      = (const float*)d_in[5];
  const float* b_off      = (const float*)d_in[6];
  const float* W_attn     = (const float*)d_in[7];
  const float* b_attn     = (const float*)d_in[8];
  const float* W_out      = (const float*)d_in[9];
  const float* b_out      = (const float*)d_in[10];

  char* w = (char*)d_ws;
  size_t o = 0;
  auto carve = [&](size_t bytes) -> void* {
    void* p = (void*)(w + o);
    o += (bytes + 255) & ~(size_t)255;
    return p;
  };
  unsigned short* Wval_t  = (unsigned short*)carve(256 * 256 * 2);
  unsigned short* Wcat_t  = (unsigned short*)carve(320 * 256 * 2);
  unsigned short* Wout_t  = (unsigned short*)carve(256 * 256 * 2);
  float*          bcat    = (float*)carve(320 * 4);
  unsigned short* value16 = (unsigned short*)carve((size_t)MTOT * 256 * 2);
  float*          logits  = (float*)carve((size_t)MTOT * 288 * 4);
  unsigned short* samp_bf = (unsigned short*)carve((size_t)MTOT * 256 * 2);

  prep_weights2<<<256, 320, 0, stream>>>(W_val, W_off, W_attn, W_out, b_off, b_attn,
                                         Wval_t, Wcat_t, Wout_t, bcat);

  const int mg = (MTOT + 63) / 64;               // 348
  dim3 g12(mg, 9);                               // 4 value tiles + 5 logits tiles
  gemm12_tile<<<g12, 64, 0, stream>>>(value_flat, query, Wval_t, Wcat_t,
                                      b_val, bcat, value16, logits);

  const int sgrid = (MTOT + 7) / 8;              // 2778
  msda_sample5<<<sgrid, 256, 0, stream>>>(value16, logits, refp, samp_bf);

  dim3 g3(mg, 4);
  gemm_out_tile<<<g3, 64, 0, stream>>>(samp_bf, Wout_t, b_out, (float*)d_out);
}